// Round 16
// baseline (235.910 us; speedup 1.0000x reference)
//
#include <hip/hip_runtime.h>

typedef unsigned short ushort_t;
typedef __attribute__((ext_vector_type(8))) short bf16x8;    // 8 bf16 = 4 VGPRs
typedef __attribute__((ext_vector_type(16))) float f32x16;   // 32x32 MFMA acc

#define MAXN 8192
#define CAND_CAP 2048
#define CHUNK_CAP 8192   // single GEMM2 dispatch (round 15: beats split)

// ---- zero-prefill d_out (safety) ----
__global__ void prefill_kernel(float* __restrict__ out, int n) {
    for (int i = blockIdx.x * 256 + threadIdx.x; i < n; i += gridDim.x * 256)
        out[i] = 0.0f;
}

// ---- f32 -> bf16 cast (RNE), 8/thread ----
__global__ __launch_bounds__(256) void cast_bf16_kernel(
    const float* __restrict__ in, ushort_t* __restrict__ out, int n)
{
    int i = (blockIdx.x * 256 + threadIdx.x) * 8;
    if (i >= n) return;
    ushort_t o[8];
#pragma unroll
    for (int q = 0; q < 8; ++q) {
        unsigned u = __float_as_uint(in[i + q]);
        o[q] = (ushort_t)((u + 0x7FFFu + ((u >> 16) & 1u)) >> 16);
    }
    *(ushort4*)(out + i)     = make_ushort4(o[0], o[1], o[2], o[3]);
    *(ushort4*)(out + i + 4) = make_ushort4(o[4], o[5], o[6], o[7]);
}

// async global->LDS, 16B per lane; lds dest = wave-uniform base + lane*16
__device__ __forceinline__ void gload_lds16(const ushort_t* g, void* lds) {
    __builtin_amdgcn_global_load_lds(
        (const __attribute__((address_space(1))) unsigned int*)g,
        (__attribute__((address_space(3))) unsigned int*)lds, 16, 0, 0);
}

// ---- GEMM1 kernel: 128x128 tile (proven 4 blk/CU config, round 11-15) ----
// C[i][j] = bf16(sum_k A[i][k]*B[j][k] + bias[j]); 2D grid.
__global__ __launch_bounds__(256, 4) void gemm_bf16_nt(
    const ushort_t* __restrict__ A, const ushort_t* __restrict__ B,
    const float* __restrict__ bias, ushort_t* __restrict__ C,
    int K, int ldc)
{
    const int bx = blockIdx.x, by = blockIdx.y;
    const int j0 = bx * 128;

    __shared__ __align__(16) ushort_t sA[128 * 64];
    __shared__ __align__(16) ushort_t sB[128 * 64];

    const int tid   = threadIdx.x;
    const int lane  = tid & 63;
    const int w     = tid >> 6;
    const int wr    = (w >> 1) * 64;
    const int wc    = (w & 1) * 64;
    const int l31   = lane & 31;
    const int khalf = lane >> 5;

    const ushort_t* Ab = A + (size_t)by * 128 * K;
    const ushort_t* Bb = B + (size_t)bx * 128 * K;

    f32x16 acc[2][2];
#pragma unroll
    for (int r = 0; r < 2; ++r)
#pragma unroll
        for (int c = 0; c < 2; ++c)
#pragma unroll
            for (int e = 0; e < 16; ++e) acc[r][c][e] = 0.0f;

    for (int k0 = 0; k0 < K; k0 += 64) {
#pragma unroll
        for (int qq = 0; qq < 4; ++qq) {
            int id = tid + qq * 256;
            int m  = id >> 3;
            int kc = ((id & 7) ^ (m & 7)) * 8;
            unsigned lb = (unsigned)(((tid & ~63) + qq * 256) * 16);
            gload_lds16(Ab + (size_t)m * K + k0 + kc, (char*)sA + lb);
            gload_lds16(Bb + (size_t)m * K + k0 + kc, (char*)sB + lb);
        }
        __syncthreads();

#pragma unroll
        for (int h = 0; h < 4; ++h) {
            const int kq = h * 2 + khalf;
            bf16x8 fa[2], fb[2];
#pragma unroll
            for (int r = 0; r < 2; ++r) {
                int m = wr + r * 32 + l31;
                fa[r] = *(const bf16x8*)&sA[(m * 8 + (kq ^ (m & 7))) * 8];
            }
#pragma unroll
            for (int c = 0; c < 2; ++c) {
                int m = wc + c * 32 + l31;
                fb[c] = *(const bf16x8*)&sB[(m * 8 + (kq ^ (m & 7))) * 8];
            }
#pragma unroll
            for (int r = 0; r < 2; ++r)
#pragma unroll
                for (int c = 0; c < 2; ++c)
                    acc[r][c] = __builtin_amdgcn_mfma_f32_32x32x16_bf16(
                        fa[r], fb[c], acc[r][c], 0, 0, 0);
        }
        __syncthreads();
    }

#pragma unroll
    for (int r = 0; r < 2; ++r) {
#pragma unroll
        for (int c = 0; c < 2; ++c) {
            int colg = j0 + wc + c * 32 + l31;
            float bv = bias ? bias[colg] : 0.0f;
#pragma unroll
            for (int reg = 0; reg < 16; ++reg) {
                int rowl = (reg & 3) + 8 * (reg >> 2) + 4 * khalf;
                int row = by * 128 + wr + r * 32 + rowl;
                float v = acc[r][c][reg] + bv;
                unsigned u = __float_as_uint(v);
                C[(size_t)row * ldc + colg] =
                    (ushort_t)((u + 0x7FFFu + ((u >> 16) & 1u)) >> 16);
            }
        }
    }
}

// ---- GEMM2 kernel: 128x256 tile, wave tile 64x128 = 2x4 of 32x32x16 ----
// Round-16: 6 ds_read per 8 MFMA (vs 1:1 at 64x64) and 0.75x staging bytes
// per output. Register budget kept under 256 unified (round-10 fix): acc 128
// + fa[2](8) + fb[1](4) via c-outer loop -> ~180 => 2 blocks/CU
// (__launch_bounds__(256,2)); LDS 48KB x2 = 96KB. PACKED triangular grid:
// 256-wide col tiles, nbx(gby) = gby/2 + 1 live tiles per 128-row block.
// No bias (GEMM2-only). C bf16, LOCAL row indexing.
__global__ __launch_bounds__(256, 2) void gemm_bf16_wide(
    const ushort_t* __restrict__ A, const ushort_t* __restrict__ B,
    ushort_t* __restrict__ C, int K, int ldc, int tbase)
{
    int f = blockIdx.x;
    int b = 0, off = 0;
    while (off + ((tbase + b) >> 1) + 1 <= f) { off += ((tbase + b) >> 1) + 1; ++b; }
    const int by = b;
    const int bx = f - off;
    const int j0 = bx * 256;

    __shared__ __align__(16) ushort_t sA[128 * 64];   // 16 KB
    __shared__ __align__(16) ushort_t sB[256 * 64];   // 32 KB

    const int tid   = threadIdx.x;
    const int lane  = tid & 63;
    const int w     = tid >> 6;
    const int wr    = (w >> 1) * 64;     // 0 / 64
    const int wc    = (w & 1) * 128;     // 0 / 128
    const int l31   = lane & 31;
    const int khalf = lane >> 5;

    const ushort_t* Ab = A + (size_t)by * 128 * K;
    const ushort_t* Bb = B + (size_t)bx * 256 * K;

    f32x16 acc[2][4];
#pragma unroll
    for (int r = 0; r < 2; ++r)
#pragma unroll
        for (int c = 0; c < 4; ++c)
#pragma unroll
            for (int e = 0; e < 16; ++e) acc[r][c][e] = 0.0f;

    for (int k0 = 0; k0 < K; k0 += 64) {
        // A: 1024 16B slots (4/thread); B: 2048 slots (8/thread)
#pragma unroll
        for (int qq = 0; qq < 4; ++qq) {
            int id = tid + qq * 256;
            int m  = id >> 3;
            int kc = ((id & 7) ^ (m & 7)) * 8;
            unsigned lb = (unsigned)(((tid & ~63) + qq * 256) * 16);
            gload_lds16(Ab + (size_t)m * K + k0 + kc, (char*)sA + lb);
        }
#pragma unroll
        for (int qq = 0; qq < 8; ++qq) {
            int id = tid + qq * 256;
            int m  = id >> 3;
            int kc = ((id & 7) ^ (m & 7)) * 8;
            unsigned lb = (unsigned)(((tid & ~63) + qq * 256) * 16);
            gload_lds16(Bb + (size_t)m * K + k0 + kc, (char*)sB + lb);
        }
        __syncthreads();

#pragma unroll
        for (int h = 0; h < 4; ++h) {
            const int kq = h * 2 + khalf;
            bf16x8 fa[2];
#pragma unroll
            for (int r = 0; r < 2; ++r) {
                int m = wr + r * 32 + l31;
                fa[r] = *(const bf16x8*)&sA[(m * 8 + (kq ^ (m & 7))) * 8];
            }
#pragma unroll
            for (int c = 0; c < 4; ++c) {
                int m = wc + c * 32 + l31;
                bf16x8 fb = *(const bf16x8*)&sB[(m * 8 + (kq ^ (m & 7))) * 8];
#pragma unroll
                for (int r = 0; r < 2; ++r)
                    acc[r][c] = __builtin_amdgcn_mfma_f32_32x32x16_bf16(
                        fa[r], fb, acc[r][c], 0, 0, 0);
            }
        }
        __syncthreads();
    }

    // Epilogue. 32x32 C/D layout (m74/m101): col = lane&31,
    // row = (reg&3) + 8*(reg>>2) + 4*(lane>>5). Store bf16 RNE.
#pragma unroll
    for (int r = 0; r < 2; ++r) {
#pragma unroll
        for (int c = 0; c < 4; ++c) {
            int colg = j0 + wc + c * 32 + l31;
#pragma unroll
            for (int reg = 0; reg < 16; ++reg) {
                int rowl = (reg & 3) + 8 * (reg >> 2) + 4 * khalf;
                int row = by * 128 + wr + r * 32 + rowl;   // local row
                float v = acc[r][c][reg];
                unsigned u = __float_as_uint(v);
                C[(size_t)row * ldc + colg] =
                    (ushort_t)((u + 0x7FFFu + ((u >> 16) & 1u)) >> 16);
            }
        }
    }
}

// ---- fully-guarded naive fp32 NT GEMM -> f32 C (fallback only) ----
__global__ __launch_bounds__(256) void gemm_nt_naive(
    const float* __restrict__ A, const float* __restrict__ B,
    const float* __restrict__ bias, float* __restrict__ C,
    int K, int ldc, int rows, int cols)
{
    int j = blockIdx.x * 16 + (threadIdx.x & 15);
    int i = blockIdx.y * 16 + (threadIdx.x >> 4);
    if (i >= rows || j >= cols) return;
    float acc = bias ? bias[j] : 0.0f;
    const float* Ar = A + (size_t)i * K;
    const float* Br = B + (size_t)j * K;
    for (int k = 0; k < K; ++k) acc = fmaf(Ar[k], Br[k], acc);
    C[(size_t)i * ldc + j] = acc;
}

// ---- f32 -> bf16 strip cast (fallback) ----
__global__ __launch_bounds__(256) void cast_bf16_n_kernel(
    const float* __restrict__ in, ushort_t* __restrict__ out, size_t n)
{
    size_t i = (size_t)blockIdx.x * 256 + threadIdx.x;
    for (; i < n; i += (size_t)gridDim.x * 256) {
        unsigned u = __float_as_uint(in[i]);
        out[i] = (ushort_t)((u + 0x7FFFu + ((u >> 16) & 1u)) >> 16);
    }
}

// ---- threshold-pruned top-k per row on bf16 scores ----
__device__ __forceinline__ unsigned mono16(unsigned b) {
    return (b & 0x8000u) ? (~b & 0xFFFFu) : (b | 0x8000u);
}
__device__ __forceinline__ float inv_mono16(unsigned m) {
    unsigned b = (m & 0x8000u) ? (m & 0x7FFFu) : (~m & 0xFFFFu);
    return __uint_as_float(b << 16);
}
__device__ __forceinline__ float scrub(float v) {
    unsigned u = __float_as_uint(v);
    if (((u >> 23) & 0xFFu) == 0xFFu) return -1.0e30f;
    if (v < -1.0e37f) return -1.0e30f;
    return v;
}

// One block per row i = row_offset + blockIdx.x; S rows bf16, width N.
// VECTORIZED ownership — thread t owns 4 chunks of 8 consecutive values:
// j = c*2048 + t*8 + e (uint4 loads, 1KB/wave-instr).
//  1. per-thread register max, no atomics;
//  2. radix-select k-th largest of 256 maxima -> L (guarantee: >=k threads
//     have max >= L, each contributes >=1 value >= L => count(>=L) >= k);
//  3. compact values >= L, rank-by-count (keys unique).
// Key = (mono16<<13)|(8191-j): max = max score, ties -> smaller j (JAX).
__global__ __launch_bounds__(256) void topk_kernel(
    const ushort_t* __restrict__ S, int N, int row_offset, int k_out,
    float* __restrict__ out_s, float* __restrict__ out_i)
{
    const int i = row_offset + blockIdx.x;
    const ushort_t* row = S + (size_t)blockIdx.x * N;
    const int t = threadIdx.x;
    const int lane = t & 63;
    const int w = t >> 6;
    const int nval = (i < N) ? i : N;
    const bool vec_ok = (N % 8) == 0;

    __shared__ unsigned hist4[4][257];
    __shared__ unsigned cand[CAND_CAP];
    __shared__ unsigned cand_cnt;
    __shared__ unsigned sT1, sAbove1, sT2;

    unsigned m16[32];
    unsigned tmax = 0;
#pragma unroll
    for (int c = 0; c < 4; ++c) {
        int jb = c * 2048 + t * 8;
        if (jb < nval) {
            ushort_t vv[8];
            if (vec_ok && jb + 8 <= N) {
                *(uint4*)vv = *(const uint4*)(row + jb);
            } else {
#pragma unroll
                for (int e = 0; e < 8; ++e) vv[e] = (jb + e < N) ? row[jb + e] : 0;
            }
#pragma unroll
            for (int e = 0; e < 8; ++e) {
                unsigned m = (jb + e < nval) ? mono16(vv[e]) : 0u;
                m16[c * 8 + e] = m;
                if (m > tmax) tmax = m;
            }
        } else {
#pragma unroll
            for (int e = 0; e < 8; ++e) m16[c * 8 + e] = 0u;
        }
    }

    if (t == 0) { sT1 = 0; sAbove1 = 0; sT2 = 0; cand_cnt = 0; }
#pragma unroll
    for (int q = 0; q < 4; ++q) hist4[q][t] = 0;
    __syncthreads();

    // Pass 1: histogram of thread-maxima top bytes (ONE atomic per thread)
    if (tmax) atomicAdd(&hist4[w][tmax >> 8], 1u);
    __syncthreads();
    if (w == 0) {
        int base = lane * 4;
        unsigned h[4];
#pragma unroll
        for (int r = 0; r < 4; ++r)
            h[r] = hist4[0][base + r] + hist4[1][base + r] +
                   hist4[2][base + r] + hist4[3][base + r];
        unsigned lsum = h[0] + h[1] + h[2] + h[3];
        unsigned suf = lsum;
#pragma unroll
        for (int off = 1; off < 64; off <<= 1) {
            unsigned o = __shfl_down(suf, off, 64);
            suf += (lane + off < 64) ? o : 0u;
        }
        unsigned Sr[5];
        Sr[4] = suf - lsum;
#pragma unroll
        for (int r = 3; r >= 0; --r) Sr[r] = Sr[r + 1] + h[r];
#pragma unroll
        for (int r = 0; r < 4; ++r)
            if (Sr[r] >= (unsigned)k_out && Sr[r + 1] < (unsigned)k_out) {
                sT1 = (unsigned)(base + r);
                sAbove1 = Sr[r + 1];
            }
    }
    __syncthreads();
    const unsigned T1 = sT1, above1 = sAbove1;

    // Pass 2: low byte of maxima within bin T1
#pragma unroll
    for (int q = 0; q < 4; ++q) hist4[q][t] = 0;
    __syncthreads();
    if (tmax && (tmax >> 8) == T1) atomicAdd(&hist4[w][tmax & 255u], 1u);
    __syncthreads();
    if (w == 0) {
        unsigned need = (unsigned)k_out - above1;
        int base = lane * 4;
        unsigned h[4];
#pragma unroll
        for (int r = 0; r < 4; ++r)
            h[r] = hist4[0][base + r] + hist4[1][base + r] +
                   hist4[2][base + r] + hist4[3][base + r];
        unsigned lsum = h[0] + h[1] + h[2] + h[3];
        unsigned suf = lsum;
#pragma unroll
        for (int off = 1; off < 64; off <<= 1) {
            unsigned o = __shfl_down(suf, off, 64);
            suf += (lane + off < 64) ? o : 0u;
        }
        unsigned Sr[5];
        Sr[4] = suf - lsum;
#pragma unroll
        for (int r = 3; r >= 0; --r) Sr[r] = Sr[r + 1] + h[r];
#pragma unroll
        for (int r = 0; r < 4; ++r)
            if (Sr[r] >= need && Sr[r + 1] < need)
                sT2 = (unsigned)(base + r);
    }
    __syncthreads();
    const unsigned Lt = (T1 << 8) | sT2;   // k-th largest thread-max (or 0)

    // Compact all row values >= Lt
#pragma unroll
    for (int s = 0; s < 32; ++s) {
        unsigned m = m16[s];
        if (m && m >= Lt) {
            unsigned idx = atomicAdd(&cand_cnt, 1u);
            if (idx < CAND_CAP) {
                int j = (s >> 3) * 2048 + t * 8 + (s & 7);
                cand[idx] = (m << 13) | (unsigned)(8191 - j);
            }
        }
    }
    __syncthreads();

    // Rank-by-counting extraction (keys unique -> ranks unique)
    const int m = (cand_cnt < CAND_CAP) ? (int)cand_cnt : CAND_CAP;
    const int reals = (k_out < nval) ? k_out : nval;
    for (int c = t; c < m; c += 256) {
        unsigned key = cand[c];
        int rank = 0;
        for (int x = 0; x < m; ++x) rank += (cand[x] > key) ? 1 : 0;
        if (rank < reals) {
            out_s[(size_t)i * k_out + rank] = scrub(inv_mono16(key >> 13));
            out_i[(size_t)i * k_out + rank] = (float)(8191 - (int)(key & 0x1FFFu));
        }
    }
    for (int r = reals + t; r < k_out; r += 256) {
        out_s[(size_t)i * k_out + r] = -1.0e30f;
        out_i[(size_t)i * k_out + r] = (float)r;
    }
}

extern "C" void kernel_launch(void* const* d_in, const int* in_sizes, int n_in,
                              void* d_out, int out_size, void* d_ws, size_t ws_size,
                              hipStream_t stream)
{
    const float* mentions = (const float*)d_in[0];   // [N x F]
    const float* W        = (const float*)d_in[1];   // [F x F]
    const float* bias     = (const float*)d_in[2];   // [F]

    const int F = in_sizes[2] > 0 ? in_sizes[2] : 1;
    const int N = in_sizes[0] / F;
    const int k_out = (N > 0) ? out_size / (2 * N) : 0;

    float* out_s = (float*)d_out;
    float* out_i = out_s + (size_t)N * k_out;

    prefill_kernel<<<256, 256, 0, stream>>>((float*)d_out, out_size);
    if (N <= 0 || k_out <= 0 || N > MAXN) return;

    dim3 blk(256);
    const bool tile_ok = (N % 256 == 0) && (F % 128 == 0);

    if (tile_ok) {
        // ws layout (bf16): Mb | Wb | Pb | sbuf
        ushort_t* Mb = (ushort_t*)d_ws;                    // N*F
        ushort_t* Wb = Mb + (size_t)N * F;                 // F*F
        ushort_t* Pb = Wb + (size_t)F * F;                 // N*F
        size_t fixed = ((size_t)2 * N * F + (size_t)F * F) * sizeof(ushort_t);
        size_t off = (fixed + 255) & ~(size_t)255;
        ushort_t* sbuf = (ushort_t*)((char*)d_ws + off);

        int chunk = (N < CHUNK_CAP) ? N : CHUNK_CAP;
        while (chunk > 256 && off + (size_t)chunk * N * sizeof(ushort_t) > ws_size)
            chunk >>= 1;

        if (off + (size_t)chunk * N * sizeof(ushort_t) <= ws_size) {
            cast_bf16_kernel<<<(N * F / 8 + 255) / 256, blk, 0, stream>>>(
                mentions, Mb, N * F);
            cast_bf16_kernel<<<(F * F / 8 + 255) / 256, blk, 0, stream>>>(
                W, Wb, F * F);

            // GEMM1: Pb = bf16(mentions @ W^T + b)   [N x F]  (128x128 kernel)
            gemm_bf16_nt<<<dim3(F / 128, N / 128), blk, 0, stream>>>(
                Mb, Wb, bias, Pb, F, F);

            // GEMM2: packed triangular grid of 128x256 tiles + top-k
            for (int r0 = 0; r0 < N; r0 += chunk) {
                int rows = (N - r0 < chunk) ? (N - r0) : chunk;
                int nby = rows / 128, base = r0 / 128;
                int T = 0;
                for (int b = 0; b < nby; ++b) T += ((base + b) >> 1) + 1;
                gemm_bf16_wide<<<dim3(T, 1), blk, 0, stream>>>(
                    Pb + (size_t)r0 * F, Mb, sbuf, F, N, base);
                topk_kernel<<<rows, blk, 0, stream>>>(sbuf, N, r0, k_out, out_s, out_i);
            }
            return;
        }
    }

    // ---- fallback: naive f32 GEMMs + f32->bf16 cast of the score chunk ----
    {
        float* projf = (float*)d_ws;                           // N*F f32
        size_t o1 = (((size_t)N * F * sizeof(float)) + 255) & ~(size_t)255;
        float* sf = (float*)((char*)d_ws + o1);                // chunk*N f32
        int chunk = ((N + 127) / 128) * 128;
        while (chunk > 128 &&
               o1 + (size_t)chunk * N * (sizeof(float) + sizeof(ushort_t)) > ws_size)
            chunk >>= 1;
        size_t o2 = o1 + (((size_t)chunk * N * sizeof(float) + 255) & ~(size_t)255);
        ushort_t* sb = (ushort_t*)((char*)d_ws + o2);          // chunk*N bf16

        gemm_nt_naive<<<dim3((F + 15) / 16, (N + 15) / 16), blk, 0, stream>>>(
            mentions, W, bias, projf, F, F, N, F);
        for (int r0 = 0; r0 < N; r0 += chunk) {
            int rows = (N - r0 < chunk) ? (N - r0) : chunk;
            gemm_nt_naive<<<dim3((r0 + rows + 15) / 16, (rows + 15) / 16), blk, 0, stream>>>(
                projf + (size_t)r0 * F, mentions, nullptr, sf, F, N, rows, r0 + rows);
            cast_bf16_n_kernel<<<1024, blk, 0, stream>>>(sf, sb, (size_t)rows * N);
            topk_kernel<<<rows, blk, 0, stream>>>(sb, N, r0, k_out, out_s, out_i);
        }
    }
}